// Round 3
// baseline (114.756 us; speedup 1.0000x reference)
//
#include <hip/hip_runtime.h>
#include <math.h>

// features: (1,50,50,1024) fp32 NHWC; boxes: (1,300,4) [y1,x1,y2,x2] in [0,1]
// CROP=14, POOL_K=2 -> out (1,300,7,7,1024) fp32
#define FH 50
#define FW 50
#define FC4 256    // float4s per pixel (1024 ch / 4)
#define NBOX 300
#define PO 7

typedef float nat4 __attribute__((ext_vector_type(4)));

__device__ __forceinline__ nat4 lerp4(nat4 a, nat4 b, float w) {
    return a + (b - a) * w;
}
__device__ __forceinline__ nat4 max4(nat4 a, nat4 b) {
    nat4 r;
    r.x = fmaxf(a.x, b.x);
    r.y = fmaxf(a.y, b.y);
    r.z = fmaxf(a.z, b.z);
    r.w = fmaxf(a.w, b.w);
    return r;
}

// One block per (box, pooled row). 256 threads x float4 = 1024 channels.
// Box->XCD affinity: all 7 row-strips of box n land on the same XCD under
// either round-robin or chunked block->XCD mapping.
// Software-pipelined column walk: loads for column ix+1 are issued before
// computing sample ix, so L2 latency overlaps the bilinear VALU work.
__global__ __launch_bounds__(256) void roi_pool_kernel(
    const float* __restrict__ feat,    // (50,50,1024)
    const float* __restrict__ boxes,   // (300,4)
    float* __restrict__ out)           // (300,7,7,1024)
{
    const int j = blockIdx.x & 7;
    const int k = blockIdx.x >> 3;
    const int n = j + 8 * (k / PO);
    const int py = k % PO;
    if (n >= NBOX) return;
    const int c4 = threadIdx.x;        // channel float4 index 0..255

    // Box coords — block-uniform.
    const float by1 = boxes[n * 4 + 0];
    const float bx1 = boxes[n * 4 + 1];
    const float by2 = boxes[n * 4 + 2];
    const float bx2 = boxes[n * 4 + 3];

    const float stepy = (by2 - by1) * (49.0f / 13.0f);
    const float stepx = (bx2 - bx1) * (49.0f / 13.0f);
    const float basey = by1 * 49.0f;
    const float basex = bx1 * 49.0f;

    // Two crop rows for this pooled row: iy = 2*py, 2*py+1.
    const float ysA = basey + (float)(2 * py) * stepy;
    const float ysB = ysA + stepy;
    const float fA = floorf(ysA); const float wyA = ysA - fA;
    const float fB = floorf(ysB); const float wyB = ysB - fB;
    const int y0A = min(max((int)fA, 0), FH - 1); const int y1A = min(y0A + 1, FH - 1);
    const int y0B = min(max((int)fB, 0), FH - 1); const int y1B = min(y0B + 1, FH - 1);

    const nat4* __restrict__ f4 = reinterpret_cast<const nat4*>(feat);
    const int rows[4] = { y0A * FW, y1A * FW, y0B * FW, y1B * FW };

    nat4 cur[4][2];   // [row][col]: cols (curx0, min(curx0+1,49))
    nat4 nxt[4][2];   // incoming loads for the next column pair

    // Prologue: issue + use sample-0 columns (one unavoidable stall).
    int curx0;
    {
        const float xf = floorf(basex);
        curx0 = min(max((int)xf, 0), FW - 1);
        const int x1 = min(curx0 + 1, FW - 1);
        #pragma unroll
        for (int r = 0; r < 4; ++r) {
            cur[r][0] = f4[(rows[r] + curx0) * FC4 + c4];
            cur[r][1] = f4[(rows[r] + x1   ) * FC4 + c4];
        }
    }

    nat4 m = (nat4)(-INFINITY);
    nat4* __restrict__ obase =
        reinterpret_cast<nat4*>(out) + (size_t)(n * (PO * PO) + py * PO) * FC4 + c4;

    #pragma unroll
    for (int ix = 0; ix < 2 * PO; ++ix) {
        // ---- Issue loads for column ix+1 (addresses are load-independent) ----
        int d = 0;
        if (ix < 2 * PO - 1) {
            const float xsn = basex + (float)(ix + 1) * stepx;
            const int nx0 = min(max((int)floorf(xsn), 0), FW - 1);
            const int nx1 = min(nx0 + 1, FW - 1);
            d = nx0 - curx0;
            if (d == 1) {
                #pragma unroll
                for (int r = 0; r < 4; ++r)
                    nxt[r][1] = f4[(rows[r] + nx1) * FC4 + c4];
            } else if (d >= 2) {
                #pragma unroll
                for (int r = 0; r < 4; ++r) {
                    nxt[r][0] = f4[(rows[r] + nx0) * FC4 + c4];
                    nxt[r][1] = f4[(rows[r] + nx1) * FC4 + c4];
                }
            }
            curx0 = nx0;
        }

        // ---- Compute sample ix from current registers ----
        {
            const float xs = basex + (float)ix * stepx;
            const float wx = xs - floorf(xs);     // unclipped floor for the weight
            const nat4 vA = lerp4(lerp4(cur[0][0], cur[0][1], wx),
                                  lerp4(cur[1][0], cur[1][1], wx), wyA);
            const nat4 vB = lerp4(lerp4(cur[2][0], cur[2][1], wx),
                                  lerp4(cur[3][0], cur[3][1], wx), wyB);
            m = max4(m, max4(vA, vB));
        }

        if (ix & 1) {
            // write-once output: keep it out of L2 so features stay resident
            __builtin_nontemporal_store(m, obase + (ix >> 1) * FC4);
            m = (nat4)(-INFINITY);
        }

        // ---- Rotate incoming -> current ----
        if (ix < 2 * PO - 1) {
            if (d == 1) {
                #pragma unroll
                for (int r = 0; r < 4; ++r) {
                    cur[r][0] = cur[r][1];
                    cur[r][1] = nxt[r][1];
                }
            } else if (d >= 2) {
                #pragma unroll
                for (int r = 0; r < 4; ++r) {
                    cur[r][0] = nxt[r][0];
                    cur[r][1] = nxt[r][1];
                }
            }
        }
    }
}

extern "C" void kernel_launch(void* const* d_in, const int* in_sizes, int n_in,
                              void* d_out, int out_size, void* d_ws, size_t ws_size,
                              hipStream_t stream) {
    const float* feat  = (const float*)d_in[0];  // (1,50,50,1024)
    const float* boxes = (const float*)d_in[1];  // (1,300,4)
    float* out = (float*)d_out;                  // (1,300,7,7,1024)

    // 8 XCD slots x ceil(300/8)=38 boxes x 7 pooled rows = 2128 blocks
    dim3 grid(8 * 38 * PO);
    dim3 block(256);
    roi_pool_kernel<<<grid, block, 0, stream>>>(feat, boxes, out);
}

// Round 4
// 107.024 us; speedup vs baseline: 1.0722x; 1.0722x over previous
//
#include <hip/hip_runtime.h>
#include <math.h>

// features: (1,50,50,1024) fp32 NHWC; boxes: (1,300,4) [y1,x1,y2,x2] in [0,1]
// CROP=14, POOL_K=2 -> out (1,300,7,7,1024) fp32
#define FH 50
#define FW 50
#define FC4 256    // float4s per pixel (1024 ch / 4)
#define NBOX 300
#define PO 7
#define CHQ 4      // channel quarters: 4 blocks x 64 threads cover 1024 ch

typedef float nat4 __attribute__((ext_vector_type(4)));

__device__ __forceinline__ nat4 lerp4(nat4 a, nat4 b, float w) {
    return a + (b - a) * w;
}
__device__ __forceinline__ nat4 max4(nat4 a, nat4 b) {
    nat4 r;
    r.x = fmaxf(a.x, b.x);
    r.y = fmaxf(a.y, b.y);
    r.z = fmaxf(a.z, b.z);
    r.w = fmaxf(a.w, b.w);
    return r;
}

// One SINGLE-WAVE block per (box, pooled row, channel-quarter).
// 64 threads x float4 = 256 channels per block; 4 blocks per strip.
// Low VGPR (rolling 4x2 column cache, no software pipeline) -> 8 waves/SIMD
// cap; 8512 blocks ~= 33 waves/CU of work -> latency hidden by TLP.
// Box->XCD affinity keeps a box's 28 blocks on one XCD's L2.
__global__ __launch_bounds__(64) void roi_pool_kernel(
    const float* __restrict__ feat,    // (50,50,1024)
    const float* __restrict__ boxes,   // (300,4)
    float* __restrict__ out)           // (300,7,7,1024)
{
    const int j = blockIdx.x & 7;              // XCD slot
    const int k = blockIdx.x >> 3;
    const int n = j + 8 * (k / (PO * CHQ));    // box
    if (n >= NBOX) return;
    const int r  = k % (PO * CHQ);
    const int py = r >> 2;                     // pooled row 0..6
    const int cq = r & 3;                      // channel quarter 0..3
    const int c4 = cq * 64 + threadIdx.x;      // float4 channel index 0..255

    // Box coords — block-uniform scalar loads.
    const float by1 = boxes[n * 4 + 0];
    const float bx1 = boxes[n * 4 + 1];
    const float by2 = boxes[n * 4 + 2];
    const float bx2 = boxes[n * 4 + 3];

    const float stepy = (by2 - by1) * (49.0f / 13.0f);
    const float stepx = (bx2 - bx1) * (49.0f / 13.0f);
    const float basey = by1 * 49.0f;
    const float basex = bx1 * 49.0f;

    // Two crop rows for this pooled row: iy = 2*py, 2*py+1.
    const float ysA = basey + (float)(2 * py) * stepy;
    const float ysB = ysA + stepy;
    const float fA = floorf(ysA); const float wyA = ysA - fA;
    const float fB = floorf(ysB); const float wyB = ysB - fB;
    const int y0A = min(max((int)fA, 0), FH - 1); const int y1A = min(y0A + 1, FH - 1);
    const int y0B = min(max((int)fB, 0), FH - 1); const int y1B = min(y0B + 1, FH - 1);

    const nat4* __restrict__ f4 = reinterpret_cast<const nat4*>(feat);
    const int rA0 = y0A * FW, rA1 = y1A * FW, rB0 = y0B * FW, rB1 = y1B * FW;

    // Rolling register column-cache: cols (cc, min(cc+1,49)) for the 4 rows.
    int cc = -1000;
    nat4 A00, A01, A10, A11, B00, B01, B10, B11;
    A00 = A01 = A10 = A11 = B00 = B01 = B10 = B11 = (nat4)0.0f;

    nat4 m = (nat4)(-INFINITY);
    nat4* __restrict__ obase =
        reinterpret_cast<nat4*>(out) + (size_t)(n * (PO * PO) + py * PO) * FC4 + c4;

    for (int ix = 0; ix < 2 * PO; ++ix) {
        const float xs = basex + (float)ix * stepx;
        const float xf = floorf(xs);
        const float wx = xs - xf;              // unclipped floor for the weight
        int x0 = min(max((int)xf, 0), FW - 1);
        const int x1 = min(x0 + 1, FW - 1);

        if (x0 != cc) {                        // wave-uniform branch
            if (x0 == cc + 1) {
                // shift: cached col1 (== x0) becomes col0; load only new col1
                A00 = A01; A10 = A11; B00 = B01; B10 = B11;
                A01 = f4[(rA0 + x1) * FC4 + c4];
                A11 = f4[(rA1 + x1) * FC4 + c4];
                B01 = f4[(rB0 + x1) * FC4 + c4];
                B11 = f4[(rB1 + x1) * FC4 + c4];
            } else {
                A00 = f4[(rA0 + x0) * FC4 + c4];
                A01 = f4[(rA0 + x1) * FC4 + c4];
                A10 = f4[(rA1 + x0) * FC4 + c4];
                A11 = f4[(rA1 + x1) * FC4 + c4];
                B00 = f4[(rB0 + x0) * FC4 + c4];
                B01 = f4[(rB0 + x1) * FC4 + c4];
                B10 = f4[(rB1 + x0) * FC4 + c4];
                B11 = f4[(rB1 + x1) * FC4 + c4];
            }
            cc = x0;
        }

        const nat4 vA = lerp4(lerp4(A00, A01, wx), lerp4(A10, A11, wx), wyA);
        const nat4 vB = lerp4(lerp4(B00, B01, wx), lerp4(B10, B11, wx), wyB);
        m = max4(m, max4(vA, vB));

        if (ix & 1) {
            // write-once output: NT store keeps it out of L2 so features stay
            __builtin_nontemporal_store(m, obase + (ix >> 1) * FC4);
            m = (nat4)(-INFINITY);
        }
    }
}

extern "C" void kernel_launch(void* const* d_in, const int* in_sizes, int n_in,
                              void* d_out, int out_size, void* d_ws, size_t ws_size,
                              hipStream_t stream) {
    const float* feat  = (const float*)d_in[0];  // (1,50,50,1024)
    const float* boxes = (const float*)d_in[1];  // (1,300,4)
    float* out = (float*)d_out;                  // (1,300,7,7,1024)

    // 8 XCD slots x ceil(300/8)=38 boxes x 7 rows x 4 channel-quarters
    dim3 grid(8 * 38 * PO * CHQ);
    dim3 block(64);
    roi_pool_kernel<<<grid, block, 0, stream>>>(feat, boxes, out);
}

// Round 5
// 99.089 us; speedup vs baseline: 1.1581x; 1.0801x over previous
//
#include <hip/hip_runtime.h>
#include <math.h>

// features: (1,50,50,1024) fp32 NHWC; boxes: (1,300,4) [y1,x1,y2,x2] in [0,1]
// CROP=14, POOL_K=2 -> out (1,300,7,7,1024) fp32
#define FH 50
#define FW 50
#define FC 1024
#define FC4 256        // float4s (fp32) or uint2s (bf16 pairs x2) per pixel
#define NBOX 300
#define PO 7
#define CHQ 4
#define NPIX (FH * FW * FC)          // 2,560,000 elements
#define BF16_BYTES (NPIX * 2)        // 5,242,880

typedef float nat4 __attribute__((ext_vector_type(4)));

__device__ __forceinline__ nat4 lerp4(nat4 a, nat4 b, float w) {
    return a + (b - a) * w;
}
__device__ __forceinline__ nat4 max4(nat4 a, nat4 b) {
    nat4 r;
    r.x = fmaxf(a.x, b.x);
    r.y = fmaxf(a.y, b.y);
    r.z = fmaxf(a.z, b.z);
    r.w = fmaxf(a.w, b.w);
    return r;
}
// unpack 4 bf16 channels (packed little-endian in uint2) to f32
__device__ __forceinline__ nat4 bf2f(uint2 u) {
    nat4 r;
    r.x = __uint_as_float(u.x << 16);
    r.y = __uint_as_float(u.x & 0xffff0000u);
    r.z = __uint_as_float(u.y << 16);
    r.w = __uint_as_float(u.y & 0xffff0000u);
    return r;
}
__device__ __forceinline__ unsigned bfpack(float a, float b) {  // RNE to bf16, pack
    unsigned ua = __float_as_uint(a);
    unsigned ub = __float_as_uint(b);
    ua += 0x7fffu + ((ua >> 16) & 1u);
    ub += 0x7fffu + ((ub >> 16) & 1u);
    return (ua >> 16) | (ub & 0xffff0000u);
}

// Pass 1: fp32 features -> bf16 in workspace. 2500 blocks x 256 threads,
// one float4 per thread. ~15 MB traffic -> ~3 us.
__global__ __launch_bounds__(256) void cvt_kernel(
    const float* __restrict__ feat, unsigned* __restrict__ ws)
{
    const int i = blockIdx.x * 256 + threadIdx.x;   // float4 index, 640,000 total
    const float4 v = reinterpret_cast<const float4*>(feat)[i];
    uint2 w;
    w.x = bfpack(v.x, v.y);
    w.y = bfpack(v.z, v.w);
    reinterpret_cast<uint2*>(ws)[i] = w;
}

// Pass 2: one SINGLE-WAVE block per (box, pooled row, channel-quarter).
// 64 threads x 4 channels (8B bf16 loads) = 256 ch/block. Rolling 4x2
// column cache held as f32 registers (converted on load). Box->XCD
// affinity + NT output stores keep the bf16 map resident in L2.
__global__ __launch_bounds__(64) void roi_pool_bf16_kernel(
    const unsigned* __restrict__ ws,   // bf16 features (50,50,1024)
    const float* __restrict__ boxes,   // (300,4)
    float* __restrict__ out)           // (300,7,7,1024)
{
    const int j = blockIdx.x & 7;              // XCD slot
    const int k = blockIdx.x >> 3;
    const int n = j + 8 * (k / (PO * CHQ));    // box
    if (n >= NBOX) return;
    const int r  = k % (PO * CHQ);
    const int py = r >> 2;                     // pooled row 0..6
    const int cq = r & 3;                      // channel quarter 0..3
    const int c  = cq * 64 + threadIdx.x;      // uint2 index in pixel, 0..255

    const float by1 = boxes[n * 4 + 0];
    const float bx1 = boxes[n * 4 + 1];
    const float by2 = boxes[n * 4 + 2];
    const float bx2 = boxes[n * 4 + 3];

    const float stepy = (by2 - by1) * (49.0f / 13.0f);
    const float stepx = (bx2 - bx1) * (49.0f / 13.0f);
    const float basey = by1 * 49.0f;
    const float basex = bx1 * 49.0f;

    const float ysA = basey + (float)(2 * py) * stepy;
    const float ysB = ysA + stepy;
    const float fA = floorf(ysA); const float wyA = ysA - fA;
    const float fB = floorf(ysB); const float wyB = ysB - fB;
    const int y0A = min(max((int)fA, 0), FH - 1); const int y1A = min(y0A + 1, FH - 1);
    const int y0B = min(max((int)fB, 0), FH - 1); const int y1B = min(y0B + 1, FH - 1);

    const uint2* __restrict__ f2 = reinterpret_cast<const uint2*>(ws);
    const int rA0 = y0A * FW, rA1 = y1A * FW, rB0 = y0B * FW, rB1 = y1B * FW;

    // Rolling f32 column cache: cols (cc, min(cc+1,49)) for the 4 rows.
    int cc = -1000;
    nat4 A00, A01, A10, A11, B00, B01, B10, B11;
    A00 = A01 = A10 = A11 = B00 = B01 = B10 = B11 = (nat4)0.0f;

    nat4 m = (nat4)(-INFINITY);
    nat4* __restrict__ obase =
        reinterpret_cast<nat4*>(out) + (size_t)(n * (PO * PO) + py * PO) * FC4 + c;

    for (int ix = 0; ix < 2 * PO; ++ix) {
        const float xs = basex + (float)ix * stepx;
        const float xf = floorf(xs);
        const float wx = xs - xf;              // unclipped floor for the weight
        int x0 = min(max((int)xf, 0), FW - 1);
        const int x1 = min(x0 + 1, FW - 1);

        if (x0 != cc) {                        // wave-uniform branch
            if (x0 == cc + 1) {
                A00 = A01; A10 = A11; B00 = B01; B10 = B11;
                A01 = bf2f(f2[(rA0 + x1) * FC4 + c]);
                A11 = bf2f(f2[(rA1 + x1) * FC4 + c]);
                B01 = bf2f(f2[(rB0 + x1) * FC4 + c]);
                B11 = bf2f(f2[(rB1 + x1) * FC4 + c]);
            } else {
                A00 = bf2f(f2[(rA0 + x0) * FC4 + c]);
                A01 = bf2f(f2[(rA0 + x1) * FC4 + c]);
                A10 = bf2f(f2[(rA1 + x0) * FC4 + c]);
                A11 = bf2f(f2[(rA1 + x1) * FC4 + c]);
                B00 = bf2f(f2[(rB0 + x0) * FC4 + c]);
                B01 = bf2f(f2[(rB0 + x1) * FC4 + c]);
                B10 = bf2f(f2[(rB1 + x0) * FC4 + c]);
                B11 = bf2f(f2[(rB1 + x1) * FC4 + c]);
            }
            cc = x0;
        }

        const nat4 vA = lerp4(lerp4(A00, A01, wx), lerp4(A10, A11, wx), wyA);
        const nat4 vB = lerp4(lerp4(B00, B01, wx), lerp4(B10, B11, wx), wyB);
        m = max4(m, max4(vA, vB));

        if (ix & 1) {
            __builtin_nontemporal_store(m, obase + (ix >> 1) * FC4);
            m = (nat4)(-INFINITY);
        }
    }
}

// Fallback (ws too small): R4's fp32 kernel, same structure.
__global__ __launch_bounds__(64) void roi_pool_f32_kernel(
    const float* __restrict__ feat,
    const float* __restrict__ boxes,
    float* __restrict__ out)
{
    const int j = blockIdx.x & 7;
    const int k = blockIdx.x >> 3;
    const int n = j + 8 * (k / (PO * CHQ));
    if (n >= NBOX) return;
    const int r  = k % (PO * CHQ);
    const int py = r >> 2;
    const int cq = r & 3;
    const int c4 = cq * 64 + threadIdx.x;

    const float by1 = boxes[n * 4 + 0];
    const float bx1 = boxes[n * 4 + 1];
    const float by2 = boxes[n * 4 + 2];
    const float bx2 = boxes[n * 4 + 3];
    const float stepy = (by2 - by1) * (49.0f / 13.0f);
    const float stepx = (bx2 - bx1) * (49.0f / 13.0f);
    const float basey = by1 * 49.0f;
    const float basex = bx1 * 49.0f;
    const float ysA = basey + (float)(2 * py) * stepy;
    const float ysB = ysA + stepy;
    const float fA = floorf(ysA); const float wyA = ysA - fA;
    const float fB = floorf(ysB); const float wyB = ysB - fB;
    const int y0A = min(max((int)fA, 0), FH - 1); const int y1A = min(y0A + 1, FH - 1);
    const int y0B = min(max((int)fB, 0), FH - 1); const int y1B = min(y0B + 1, FH - 1);

    const nat4* __restrict__ f4 = reinterpret_cast<const nat4*>(feat);
    const int rA0 = y0A * FW, rA1 = y1A * FW, rB0 = y0B * FW, rB1 = y1B * FW;

    int cc = -1000;
    nat4 A00, A01, A10, A11, B00, B01, B10, B11;
    A00 = A01 = A10 = A11 = B00 = B01 = B10 = B11 = (nat4)0.0f;
    nat4 m = (nat4)(-INFINITY);
    nat4* __restrict__ obase =
        reinterpret_cast<nat4*>(out) + (size_t)(n * (PO * PO) + py * PO) * FC4 + c4;

    for (int ix = 0; ix < 2 * PO; ++ix) {
        const float xs = basex + (float)ix * stepx;
        const float xf = floorf(xs);
        const float wx = xs - xf;
        int x0 = min(max((int)xf, 0), FW - 1);
        const int x1 = min(x0 + 1, FW - 1);
        if (x0 != cc) {
            if (x0 == cc + 1) {
                A00 = A01; A10 = A11; B00 = B01; B10 = B11;
                A01 = f4[(rA0 + x1) * FC4 + c4];
                A11 = f4[(rA1 + x1) * FC4 + c4];
                B01 = f4[(rB0 + x1) * FC4 + c4];
                B11 = f4[(rB1 + x1) * FC4 + c4];
            } else {
                A00 = f4[(rA0 + x0) * FC4 + c4];
                A01 = f4[(rA0 + x1) * FC4 + c4];
                A10 = f4[(rA1 + x0) * FC4 + c4];
                A11 = f4[(rA1 + x1) * FC4 + c4];
                B00 = f4[(rB0 + x0) * FC4 + c4];
                B01 = f4[(rB0 + x1) * FC4 + c4];
                B10 = f4[(rB1 + x0) * FC4 + c4];
                B11 = f4[(rB1 + x1) * FC4 + c4];
            }
            cc = x0;
        }
        const nat4 vA = lerp4(lerp4(A00, A01, wx), lerp4(A10, A11, wx), wyA);
        const nat4 vB = lerp4(lerp4(B00, B01, wx), lerp4(B10, B11, wx), wyB);
        m = max4(m, max4(vA, vB));
        if (ix & 1) {
            __builtin_nontemporal_store(m, obase + (ix >> 1) * FC4);
            m = (nat4)(-INFINITY);
        }
    }
}

extern "C" void kernel_launch(void* const* d_in, const int* in_sizes, int n_in,
                              void* d_out, int out_size, void* d_ws, size_t ws_size,
                              hipStream_t stream) {
    const float* feat  = (const float*)d_in[0];  // (1,50,50,1024)
    const float* boxes = (const float*)d_in[1];  // (1,300,4)
    float* out = (float*)d_out;                  // (1,300,7,7,1024)

    dim3 grid(8 * 38 * PO * CHQ);   // 8512 single-wave blocks
    dim3 block(64);

    if (ws_size >= (size_t)BF16_BYTES) {
        unsigned* wsb = (unsigned*)d_ws;
        cvt_kernel<<<dim3(NPIX / 4 / 256), dim3(256), 0, stream>>>(feat, wsb);
        roi_pool_bf16_kernel<<<grid, block, 0, stream>>>(wsb, boxes, out);
    } else {
        roi_pool_f32_kernel<<<grid, block, 0, stream>>>(feat, boxes, out);
    }
}